// Round 4
// baseline (326.370 us; speedup 1.0000x reference)
//
#include <hip/hip_runtime.h>

// WindowMSA fused kernel for MI355X (gfx950).
// One block = one window (B=4096). 4 waves = 4 heads.
// All matmuls via v_mfma_f32_16x16x32_bf16, fp32 accumulate.
// R4: per-head wave ownership of QKV => wave-private slabs, ONE barrier total.
//     x read fragment-shaped straight from global (no staging). XOR-swizzled
//     unpadded LDS: 4 x 12,288 B = 49,152 B => 3 blocks/CU with margin.

typedef __bf16 bf16_t;
typedef __bf16 bf8v  __attribute__((ext_vector_type(8)));
typedef __bf16 bf4v  __attribute__((ext_vector_type(4)));
typedef float  f4v   __attribute__((ext_vector_type(4)));

#define QK_SCALE 0.17677669529663687f  // 1/sqrt(32)

__device__ __forceinline__ f4v mfma16(bf8v a, bf8v b, f4v c) {
  return __builtin_amdgcn_mfma_f32_16x16x32_bf16(a, b, c, 0, 0, 0);
}

// Swizzled element indices (8-el = 16B chunks; XOR spreads banks, keeps
// fragment reads 16B-contiguous because producers/consumers share chunks).
// Q/O: 64 rows x 32 el. K at +2048. V^T: 32 rows(d) x 64 el(tok). P: 64x64.
#define QIX(row, d) ((row) * 32 + ((((((d) >> 3) ^ (((row) >> 1) & 3)) & 3)) << 3) + ((d) & 7))
#define VIX(dd, t)  (4096 + (dd) * 64 + ((((((t) >> 3) ^ ((dd) & 7)) & 7)) << 3) + ((t) & 7))
#define PIX(n, m)   ((n) * 64 + ((((((m) >> 3) ^ ((n) & 7)) & 7)) << 3) + ((m) & 7))

// ---------------- prep: swizzle weights to B-fragment order, build CB ----------------
// wq: [t<24][kt<4][lane<64][j<8]  = bf16(qkv_w[t*16+(l&15)][kt*32+(l>>4)*8+j])
// wp: [t<8 ][kt<4][lane<64][j<8]  = bf16(proj_w[...same...])
// cbs: [w<64][h<4][n<64][l16<16][nt<4] fp32 = bias+mask at m = nt*16+l16
__global__ void prep_kernel(const float* __restrict__ mask,
                            const float* __restrict__ qkv_w,
                            const float* __restrict__ proj_w,
                            const float* __restrict__ bias_table,
                            bf16_t* __restrict__ wq,
                            bf16_t* __restrict__ wp,
                            float* __restrict__ cbs) {
  const int stride = gridDim.x * blockDim.x;
  const int tid0 = blockIdx.x * blockDim.x + threadIdx.x;
  for (int i = tid0; i < 24 * 4 * 64 * 8; i += stride) {
    int j = i & 7, l = (i >> 3) & 63, kt = (i >> 9) & 3, t = i >> 11;
    int n = t * 16 + (l & 15), k = kt * 32 + (l >> 4) * 8 + j;
    wq[i] = (bf16_t)qkv_w[n * 128 + k];
  }
  for (int i = tid0; i < 8 * 4 * 64 * 8; i += stride) {
    int j = i & 7, l = (i >> 3) & 63, kt = (i >> 9) & 3, t = i >> 11;
    int n = t * 16 + (l & 15), k = kt * 32 + (l >> 4) * 8 + j;
    wp[i] = (bf16_t)proj_w[n * 128 + k];
  }
  for (int i = tid0; i < 64 * 4 * 64 * 64; i += stride) {
    int j = i & 63;                 // l16*4 + nt
    int l16 = j >> 2, nt = j & 3;
    int m = nt * 16 + l16;
    int n = (i >> 6) & 63, h = (i >> 12) & 3, w = i >> 14;
    float v;
    if (m >= 49) {
      v = -1e30f;                    // mask out padded key columns
    } else if (n >= 49) {
      v = 0.0f;                      // padded query rows: benign logits
    } else {
      int cn = 13 * (n / 7) + n % 7;
      int mm = 48 - m;
      int cm = 13 * (mm / 7) + mm % 7;
      v = bias_table[(cn + cm) * 4 + h] + mask[(w * 49 + n) * 49 + m];
    }
    cbs[i] = v;
  }
}

// ---------------- fused window MSA ----------------
__global__ __launch_bounds__(256, 3) void msa_kernel(
    const float* __restrict__ x,
    const float* __restrict__ qkv_b,
    const float* __restrict__ proj_b,
    const bf16_t* __restrict__ wq,
    const bf16_t* __restrict__ wp,
    const float* __restrict__ cbs,
    float* __restrict__ out) {
  // Per-wave slab (12,288 B): Q[0:2048) K[2048:4096) V^T[4096:6144) (elements).
  // P[64][64] aliases Q+K after QK-fragment reads; O[64][32] aliases P after
  // PV reads. All intra-slab aliasing is single-wave, in-order DS.
  __shared__ __align__(16) bf16_t gB[4][6144];

  const int tid = threadIdx.x;
  const int wv  = tid >> 6;   // wave == head
  const int ln  = tid & 63;
  const int l16 = ln & 15;
  const int l4  = ln >> 4;    // 0..3
  const int b   = blockIdx.x;
  const int w   = b & 63;     // mask window index
  const int h   = wv;
  bf16_t* S = gB[wv];

  // ---- Phase 2: this wave's 6 QKV tiles (M=64 tok, K=128) ----
  const int tg[6] = {2 * h, 2 * h + 1, 8 + 2 * h, 9 + 2 * h, 16 + 2 * h, 17 + 2 * h};
  f4v acc[6][4];
#pragma unroll
  for (int g = 0; g < 6; ++g)
#pragma unroll
    for (int mt = 0; mt < 4; ++mt) acc[g][mt] = (f4v){0.f, 0.f, 0.f, 0.f};

  const float* xb = x + (size_t)b * (49 * 128);
#pragma unroll
  for (int kt = 0; kt < 4; ++kt) {
    bf8v a[4];
#pragma unroll
    for (int mt = 0; mt < 4; ++mt) {
      int row = mt * 16 + l16;
      f4v f0 = (f4v){0.f, 0.f, 0.f, 0.f}, f1 = (f4v){0.f, 0.f, 0.f, 0.f};
      if (row < 49) {                 // folds to true for mt<3; guards OOB for mt=3
        const float* xr = xb + row * 128 + kt * 32 + l4 * 8;
        f0 = *(const f4v*)xr;
        f1 = *(const f4v*)(xr + 4);
      }
      bf8v av = { (bf16_t)f0[0], (bf16_t)f0[1], (bf16_t)f0[2], (bf16_t)f0[3],
                  (bf16_t)f1[0], (bf16_t)f1[1], (bf16_t)f1[2], (bf16_t)f1[3] };
      a[mt] = av;
    }
    bf8v bw[6];
#pragma unroll
    for (int g = 0; g < 6; ++g)
      bw[g] = *(const bf8v*)(wq + (((tg[g] * 4 + kt) * 64 + ln) << 3));
#pragma unroll
    for (int g = 0; g < 6; ++g)
#pragma unroll
      for (int mt = 0; mt < 4; ++mt)
        acc[g][mt] = mfma16(a[mt], bw[g], acc[g][mt]);
  }

  // epilogue: +bias -> wave-private slab (no barrier!)
#pragma unroll
  for (int g = 0; g < 4; ++g) {       // Q (g 0,1), K (g 2,3)
    float bias = qkv_b[tg[g] * 16 + l16];
    int d = ((g & 1) << 4) + l16;
    int base = (g < 2) ? 0 : 2048;
    float scale = (g < 2) ? QK_SCALE : 1.0f;
#pragma unroll
    for (int mt = 0; mt < 4; ++mt)
#pragma unroll
      for (int r = 0; r < 4; ++r) {
        int row = mt * 16 + l4 * 4 + r;
        S[base + QIX(row, d)] = (bf16_t)((acc[g][mt][r] + bias) * scale);
      }
  }
#pragma unroll
  for (int g = 4; g < 6; ++g) {       // V, transposed store
    float bias = qkv_b[tg[g] * 16 + l16];
    int d = ((g & 1) << 4) + l16;
#pragma unroll
    for (int mt = 0; mt < 4; ++mt) {
      int t0 = mt * 16 + l4 * 4;
      bf4v o = { (bf16_t)(acc[g][mt][0] + bias), (bf16_t)(acc[g][mt][1] + bias),
                 (bf16_t)(acc[g][mt][2] + bias), (bf16_t)(acc[g][mt][3] + bias) };
      *(bf4v*)&S[VIX(d, t0)] = o;
    }
  }

  // ---- Phase 3: attention for head h (all wave-private) ----
  {
    f4v lg[4][4];
    bf8v qf[4], kf[4];
#pragma unroll
    for (int mt = 0; mt < 4; ++mt) {
      int row = mt * 16 + l16;
      qf[mt] = *(const bf8v*)&S[QIX(row, l4 * 8)];
      kf[mt] = *(const bf8v*)&S[2048 + QIX(row, l4 * 8)];
    }
#pragma unroll
    for (int mt = 0; mt < 4; ++mt)
#pragma unroll
      for (int nt = 0; nt < 4; ++nt)
        lg[mt][nt] = mfma16(qf[mt], kf[nt], (f4v){0.f, 0.f, 0.f, 0.f});

    // max-free clamped softmax over m; P overwrites Q+K (in-order per wave)
    const float* cbp = cbs + ((size_t)(w * 4 + h) << 12);
#pragma unroll
    for (int mt = 0; mt < 4; ++mt) {
#pragma unroll
      for (int r = 0; r < 4; ++r) {
        int row = mt * 16 + l4 * 4 + r;
        float4 cbv = *(const float4*)(cbp + (row << 6) + l16 * 4);
        float vals[4];
        vals[0] = __expf(fmaxf(lg[mt][0][r] + cbv.x, -80.f));
        vals[1] = __expf(fmaxf(lg[mt][1][r] + cbv.y, -80.f));
        vals[2] = __expf(fmaxf(lg[mt][2][r] + cbv.z, -80.f));
        vals[3] = __expf(fmaxf(lg[mt][3][r] + cbv.w, -80.f));
        float s = (vals[0] + vals[1]) + (vals[2] + vals[3]);
#pragma unroll
        for (int off = 1; off < 16; off <<= 1) s += __shfl_xor(s, off);
        float inv = 1.0f / s;
#pragma unroll
        for (int nt = 0; nt < 4; ++nt)
          S[PIX(row, nt * 16 + l16)] = (bf16_t)(vals[nt] * inv);
      }
    }

    // PV as O^T = V^T @ P^T : M=32(d), N=64(n), K=64(m)
    f4v oc[2][4];
#pragma unroll
    for (int mt = 0; mt < 2; ++mt)
#pragma unroll
      for (int nt = 0; nt < 4; ++nt) oc[mt][nt] = (f4v){0.f, 0.f, 0.f, 0.f};
#pragma unroll
    for (int ks = 0; ks < 2; ++ks) {
      bf8v vf[2], pf[4];
#pragma unroll
      for (int mt = 0; mt < 2; ++mt)
        vf[mt] = *(const bf8v*)&S[VIX(mt * 16 + l16, ks * 32 + l4 * 8)];
#pragma unroll
      for (int nt = 0; nt < 4; ++nt)
        pf[nt] = *(const bf8v*)&S[PIX(nt * 16 + l16, ks * 32 + l4 * 8)];
#pragma unroll
      for (int mt = 0; mt < 2; ++mt)
#pragma unroll
        for (int nt = 0; nt < 4; ++nt)
          oc[mt][nt] = mfma16(vf[mt], pf[nt], oc[mt][nt]);
    }
    // O[token][d_local] over consumed P (in-order per wave)
#pragma unroll
    for (int mt = 0; mt < 2; ++mt)
#pragma unroll
      for (int nt = 0; nt < 4; ++nt) {
        int n = nt * 16 + l16, d0 = mt * 16 + l4 * 4;
        bf4v o = { (bf16_t)oc[mt][nt][0], (bf16_t)oc[mt][nt][1],
                   (bf16_t)oc[mt][nt][2], (bf16_t)oc[mt][nt][3] };
        *(bf4v*)&S[QIX(n, d0)] = o;
      }
  }
  __syncthreads();   // the only barrier: O slabs become block-visible

  // ---- Phase 4: proj GEMM (M=64, N=128, K=128); wave handles 2 n-tiles ----
  {
    f4v pacc[2][4];
#pragma unroll
    for (int nj = 0; nj < 2; ++nj)
#pragma unroll
      for (int mt = 0; mt < 4; ++mt) pacc[nj][mt] = (f4v){0.f, 0.f, 0.f, 0.f};
#pragma unroll
    for (int kt = 0; kt < 4; ++kt) {
      bf8v a[4];
#pragma unroll
      for (int mt = 0; mt < 4; ++mt)
        a[mt] = *(const bf8v*)&gB[kt][QIX(mt * 16 + l16, l4 * 8)];
      bf8v bw[2];
#pragma unroll
      for (int nj = 0; nj < 2; ++nj) {
        int t = wv * 2 + nj;
        bw[nj] = *(const bf8v*)(wp + (((t * 4 + kt) * 64 + ln) << 3));
      }
#pragma unroll
      for (int nj = 0; nj < 2; ++nj)
#pragma unroll
        for (int mt = 0; mt < 4; ++mt)
          pacc[nj][mt] = mfma16(a[mt], bw[nj], pacc[nj][mt]);
    }
    float* ob = out + (size_t)b * (49 * 128);
#pragma unroll
    for (int nj = 0; nj < 2; ++nj) {
      int c = (wv * 2 + nj) * 16 + l16;
      float pb = proj_b[c];
#pragma unroll
      for (int mt = 0; mt < 4; ++mt)
#pragma unroll
        for (int r = 0; r < 4; ++r) {
          int row = mt * 16 + l4 * 4 + r;
          if (row < 49) ob[row * 128 + c] = pacc[nj][mt][r] + pb;
        }
    }
  }
}

extern "C" void kernel_launch(void* const* d_in, const int* in_sizes, int n_in,
                              void* d_out, int out_size, void* d_ws, size_t ws_size,
                              hipStream_t stream) {
  const float* x          = (const float*)d_in[0];
  const float* mask       = (const float*)d_in[1];
  const float* qkv_w      = (const float*)d_in[2];
  const float* qkv_b      = (const float*)d_in[3];
  const float* proj_w     = (const float*)d_in[4];
  const float* proj_b     = (const float*)d_in[5];
  const float* bias_table = (const float*)d_in[6];

  char* ws = (char*)d_ws;
  bf16_t* wq = (bf16_t*)ws;                       // 24*4*64*8 bf16 = 98304 B
  bf16_t* wp = (bf16_t*)(ws + 98304);             // 8*4*64*8 bf16  = 32768 B
  float*  cbs = (float*)(ws + 131072);            // 64*4*64*64 f32 = 4 MiB

  prep_kernel<<<1024, 256, 0, stream>>>(mask, qkv_w, proj_w, bias_table, wq, wp, cbs);
  msa_kernel<<<4096, 256, 0, stream>>>(x, qkv_b, proj_b, wq, wp, cbs, (float*)d_out);
}